// Round 1
// baseline (1003.976 us; speedup 1.0000x reference)
//
#include <hip/hip_runtime.h>

// GCN layer: out = scatter_add(rows, vals[:,None] * embeds[cols]) over COO edges.
// N_NODES=50000, N_EDGES=800000, D_FEAT=96 (fp32 throughout; indices int32 per harness).

#define DFEAT 96
#define QUADS 24  // DFEAT / 4 float4 per edge

__global__ void gcn_scatter_kernel(const int* __restrict__ rows,
                                   const int* __restrict__ cols,
                                   const float* __restrict__ vals,
                                   const float* __restrict__ embeds,
                                   float* __restrict__ out,
                                   int n_edges) {
    long long i = (long long)blockIdx.x * blockDim.x + threadIdx.x;
    long long total = (long long)n_edges * QUADS;
    if (i >= total) return;

    int e = (int)(i / QUADS);
    int q = (int)(i - (long long)e * QUADS);

    int r = rows[e];
    int c = cols[e];
    float v = vals[e];

    const float4* emb4 = reinterpret_cast<const float4*>(embeds + (long long)c * DFEAT);
    float4 x = emb4[q];

    float* o = out + (long long)r * DFEAT + q * 4;
    atomicAdd(o + 0, v * x.x);
    atomicAdd(o + 1, v * x.y);
    atomicAdd(o + 2, v * x.z);
    atomicAdd(o + 3, v * x.w);
}

extern "C" void kernel_launch(void* const* d_in, const int* in_sizes, int n_in,
                              void* d_out, int out_size, void* d_ws, size_t ws_size,
                              hipStream_t stream) {
    const int*   rows   = (const int*)d_in[0];
    const int*   cols   = (const int*)d_in[1];
    const float* vals   = (const float*)d_in[2];
    const float* embeds = (const float*)d_in[3];
    float*       out    = (float*)d_out;

    int n_edges = in_sizes[0];

    // Zero the output accumulator every call (harness poisons d_out with 0xAA
    // once and never re-poisons between timed replays).
    hipMemsetAsync(d_out, 0, (size_t)out_size * sizeof(float), stream);

    long long total = (long long)n_edges * QUADS;
    int block = 256;
    long long grid = (total + block - 1) / block;
    gcn_scatter_kernel<<<(int)grid, block, 0, stream>>>(rows, cols, vals, embeds,
                                                        out, n_edges);
}

// Round 2
// 153.871 us; speedup vs baseline: 6.5248x; 6.5248x over previous
//
#include <hip/hip_runtime.h>

// GCN layer: out = scatter_add(rows, vals[:,None] * embeds[cols]) over COO.
// N=50000, E=800000, D=96 (fp32; indices int32 per harness).
//
// Strategy: build CSR-by-destination in workspace each call (hist -> scan ->
// bucket scatter of (col,val) pairs), then reduce each destination node's
// bucket with a 32-lane half-wave accumulating in registers. This replaces
// 76.8M fp32 device-scope atomicAdds (R1: 1.2 GB of HBM write traffic) with
// 1.6M int atomics + plain stores.

#define DFEAT 96
#define SCAN_BS 256

__global__ void hist_kernel(const int* __restrict__ rows, int* __restrict__ counts, int E) {
    int i = blockIdx.x * blockDim.x + threadIdx.x;
    if (i < E) atomicAdd(&counts[rows[i]], 1);
}

// Per-block inclusive scan; writes exclusive partials into offsets[], block sums out.
__global__ void scan_blocks_kernel(const int* __restrict__ counts, int* __restrict__ offsets,
                                   int* __restrict__ blockSums, int N) {
    __shared__ int s[SCAN_BS];
    int tid = threadIdx.x;
    int i = blockIdx.x * SCAN_BS + tid;
    int v = (i < N) ? counts[i] : 0;
    s[tid] = v;
    __syncthreads();
    for (int off = 1; off < SCAN_BS; off <<= 1) {
        int t = (tid >= off) ? s[tid - off] : 0;
        __syncthreads();
        s[tid] += t;
        __syncthreads();
    }
    if (i < N) offsets[i] = s[tid] - v;   // exclusive within block
    if (tid == SCAN_BS - 1) blockSums[blockIdx.x] = s[tid];
}

// Single-block exclusive scan of the block sums (nb <= SCAN_BS).
__global__ void scan_sums_kernel(const int* __restrict__ blockSums, int* __restrict__ blockOffs, int nb) {
    __shared__ int s[SCAN_BS];
    int tid = threadIdx.x;
    int v = (tid < nb) ? blockSums[tid] : 0;
    s[tid] = v;
    __syncthreads();
    for (int off = 1; off < SCAN_BS; off <<= 1) {
        int t = (tid >= off) ? s[tid - off] : 0;
        __syncthreads();
        s[tid] += t;
        __syncthreads();
    }
    if (tid < nb) blockOffs[tid] = s[tid] - v;
}

__global__ void add_offsets_kernel(int* __restrict__ offsets, const int* __restrict__ blockOffs,
                                   int N, int E) {
    int i = blockIdx.x * blockDim.x + threadIdx.x;
    if (i < N) offsets[i] += blockOffs[i / SCAN_BS];
    if (i == 0) offsets[N] = E;
}

__global__ void scatter_kernel(const int* __restrict__ rows, const int* __restrict__ cols,
                               const float* __restrict__ vals, const int* __restrict__ offsets,
                               int* __restrict__ cursor, int2* __restrict__ pairs, int E) {
    int i = blockIdx.x * blockDim.x + threadIdx.x;
    if (i < E) {
        int r = rows[i];
        int p = offsets[r] + atomicAdd(&cursor[r], 1);
        pairs[p] = make_int2(cols[i], __float_as_int(vals[i]));
    }
}

// One 32-lane half-wave per node: lane l owns features l, l+32, l+64.
__global__ void accumulate_kernel(const int2* __restrict__ pairs, const int* __restrict__ offsets,
                                  const float* __restrict__ embeds, float* __restrict__ out, int N) {
    int node = blockIdx.x * (blockDim.x >> 5) + (threadIdx.x >> 5);
    int lane = threadIdx.x & 31;
    if (node >= N) return;
    int start = offsets[node];
    int end   = offsets[node + 1];
    float a0 = 0.f, a1 = 0.f, a2 = 0.f;
    for (int i = start; i < end; ++i) {
        int2 p = pairs[i];
        float v = __int_as_float(p.y);
        const float* emb = embeds + (size_t)p.x * DFEAT;
        a0 += v * emb[lane];
        a1 += v * emb[lane + 32];
        a2 += v * emb[lane + 64];
    }
    float* o = out + (size_t)node * DFEAT;
    o[lane]      = a0;
    o[lane + 32] = a1;
    o[lane + 64] = a2;
}

// Fallback (R1 baseline) if workspace is unexpectedly small.
__global__ void gcn_scatter_atomic_kernel(const int* __restrict__ rows, const int* __restrict__ cols,
                                          const float* __restrict__ vals, const float* __restrict__ embeds,
                                          float* __restrict__ out, int n_edges) {
    long long i = (long long)blockIdx.x * blockDim.x + threadIdx.x;
    long long total = (long long)n_edges * (DFEAT / 4);
    if (i >= total) return;
    int e = (int)(i / (DFEAT / 4));
    int q = (int)(i - (long long)e * (DFEAT / 4));
    int r = rows[e], c = cols[e];
    float v = vals[e];
    const float4* emb4 = reinterpret_cast<const float4*>(embeds + (long long)c * DFEAT);
    float4 x = emb4[q];
    float* o = out + (long long)r * DFEAT + q * 4;
    atomicAdd(o + 0, v * x.x);
    atomicAdd(o + 1, v * x.y);
    atomicAdd(o + 2, v * x.z);
    atomicAdd(o + 3, v * x.w);
}

extern "C" void kernel_launch(void* const* d_in, const int* in_sizes, int n_in,
                              void* d_out, int out_size, void* d_ws, size_t ws_size,
                              hipStream_t stream) {
    const int*   rows   = (const int*)d_in[0];
    const int*   cols   = (const int*)d_in[1];
    const float* vals   = (const float*)d_in[2];
    const float* embeds = (const float*)d_in[3];
    float*       out    = (float*)d_out;

    int E = in_sizes[0];
    int N = in_sizes[3] / DFEAT;
    int nb = (N + SCAN_BS - 1) / SCAN_BS;  // scan blocks

    // Workspace layout (ints unless noted):
    //   counts[N] | cursor[N] | offsets[N+1] | blockSums[nb] | blockOffs[nb] | pad | pairs[E] (int2)
    size_t need = (size_t)(2 * N + (N + 1) + 2 * nb) * sizeof(int) + 8 + (size_t)E * sizeof(int2);

    if (nb <= SCAN_BS && ws_size >= need) {
        int* counts    = (int*)d_ws;
        int* cursor    = counts + N;
        int* offsets   = cursor + N;
        int* blockSums = offsets + (N + 1);
        int* blockOffs = blockSums + nb;
        size_t head_bytes = (size_t)(2 * N + (N + 1) + 2 * nb) * sizeof(int);
        head_bytes = (head_bytes + 7) & ~(size_t)7;  // align pairs to 8B
        int2* pairs = (int2*)((char*)d_ws + head_bytes);

        // Zero counts + cursor (adjacent).
        hipMemsetAsync(d_ws, 0, (size_t)2 * N * sizeof(int), stream);

        int eb = (E + 255) / 256;
        hist_kernel<<<eb, 256, 0, stream>>>(rows, counts, E);
        scan_blocks_kernel<<<nb, SCAN_BS, 0, stream>>>(counts, offsets, blockSums, N);
        scan_sums_kernel<<<1, SCAN_BS, 0, stream>>>(blockSums, blockOffs, nb);
        add_offsets_kernel<<<(N + 255) / 256, 256, 0, stream>>>(offsets, blockOffs, N, E);
        scatter_kernel<<<eb, 256, 0, stream>>>(rows, cols, vals, offsets, cursor, pairs, E);

        int nodes_per_block = 256 / 32;  // 8
        int gb = (N + nodes_per_block - 1) / nodes_per_block;
        accumulate_kernel<<<gb, 256, 0, stream>>>(pairs, offsets, embeds, out, N);
    } else {
        hipMemsetAsync(d_out, 0, (size_t)out_size * sizeof(float), stream);
        long long total = (long long)E * (DFEAT / 4);
        int block = 256;
        long long grid = (total + block - 1) / block;
        gcn_scatter_atomic_kernel<<<(int)grid, block, 0, stream>>>(rows, cols, vals, embeds, out, E);
    }
}

// Round 3
// 108.916 us; speedup vs baseline: 9.2179x; 1.4127x over previous
//
#include <hip/hip_runtime.h>

// GCN layer: out = scatter_add(rows, vals[:,None] * embeds[cols]) over COO.
// N=50000, E=800000, D=96 (fp32; indices int32 per harness).
//
// R2: CSR-by-destination build (hist -> scan -> bucket scatter) + per-node
//     32-lane register reduction. 1004 -> 154 us vs atomic baseline.
// R3: rank trick -- hist's atomicAdd return value IS the within-row rank, so
//     the bucket scatter needs no atomics (R2's scatter was 55 us, dominated
//     by a second round of 800K contended atomics). Plus 2x unroll in the
//     latency-bound accumulate gather loop.

#define DFEAT 96
#define SCAN_BS 256

// counts[rows[i]]++ and remember each edge's arrival rank within its row.
__global__ void hist_rank_kernel(const int* __restrict__ rows, int* __restrict__ counts,
                                 int* __restrict__ rank, int E) {
    int i = blockIdx.x * blockDim.x + threadIdx.x;
    if (i < E) rank[i] = atomicAdd(&counts[rows[i]], 1);
}

// Per-block scan; writes exclusive partials into offsets[], block sums out.
__global__ void scan_blocks_kernel(const int* __restrict__ counts, int* __restrict__ offsets,
                                   int* __restrict__ blockSums, int N) {
    __shared__ int s[SCAN_BS];
    int tid = threadIdx.x;
    int i = blockIdx.x * SCAN_BS + tid;
    int v = (i < N) ? counts[i] : 0;
    s[tid] = v;
    __syncthreads();
    for (int off = 1; off < SCAN_BS; off <<= 1) {
        int t = (tid >= off) ? s[tid - off] : 0;
        __syncthreads();
        s[tid] += t;
        __syncthreads();
    }
    if (i < N) offsets[i] = s[tid] - v;   // exclusive within block
    if (tid == SCAN_BS - 1) blockSums[blockIdx.x] = s[tid];
}

// Single-block exclusive scan of the block sums (nb <= SCAN_BS).
__global__ void scan_sums_kernel(const int* __restrict__ blockSums, int* __restrict__ blockOffs, int nb) {
    __shared__ int s[SCAN_BS];
    int tid = threadIdx.x;
    int v = (tid < nb) ? blockSums[tid] : 0;
    s[tid] = v;
    __syncthreads();
    for (int off = 1; off < SCAN_BS; off <<= 1) {
        int t = (tid >= off) ? s[tid - off] : 0;
        __syncthreads();
        s[tid] += t;
        __syncthreads();
    }
    if (tid < nb) blockOffs[tid] = s[tid] - v;
}

__global__ void add_offsets_kernel(int* __restrict__ offsets, const int* __restrict__ blockOffs,
                                   int N, int E) {
    int i = blockIdx.x * blockDim.x + threadIdx.x;
    if (i < N) offsets[i] += blockOffs[i / SCAN_BS];
    if (i == 0) offsets[N] = E;
}

// Atomic-free bucket scatter using the precomputed rank.
__global__ void scatter_norank_kernel(const int* __restrict__ rows, const int* __restrict__ cols,
                                      const float* __restrict__ vals, const int* __restrict__ offsets,
                                      const int* __restrict__ rank, int2* __restrict__ pairs, int E) {
    int i = blockIdx.x * blockDim.x + threadIdx.x;
    if (i < E) {
        int p = offsets[rows[i]] + rank[i];
        pairs[p] = make_int2(cols[i], __float_as_int(vals[i]));
    }
}

// Fallback scatter with per-row cursor atomics (R2 path).
__global__ void scatter_cursor_kernel(const int* __restrict__ rows, const int* __restrict__ cols,
                                      const float* __restrict__ vals, const int* __restrict__ offsets,
                                      int* __restrict__ cursor, int2* __restrict__ pairs, int E) {
    int i = blockIdx.x * blockDim.x + threadIdx.x;
    if (i < E) {
        int r = rows[i];
        int p = offsets[r] + atomicAdd(&cursor[r], 1);
        pairs[p] = make_int2(cols[i], __float_as_int(vals[i]));
    }
}

// One 32-lane half-wave per node: lane l owns features l, l+32, l+64.
// 2x unrolled: doubles outstanding gathers in this latency-bound loop.
__global__ void accumulate_kernel(const int2* __restrict__ pairs, const int* __restrict__ offsets,
                                  const float* __restrict__ embeds, float* __restrict__ out, int N) {
    int node = blockIdx.x * (blockDim.x >> 5) + (threadIdx.x >> 5);
    int lane = threadIdx.x & 31;
    if (node >= N) return;
    int start = offsets[node];
    int end   = offsets[node + 1];
    float a0 = 0.f, a1 = 0.f, a2 = 0.f;
    int i = start;
    for (; i + 2 <= end; i += 2) {
        int2 p0 = pairs[i];
        int2 p1 = pairs[i + 1];
        const float* e0 = embeds + (size_t)p0.x * DFEAT;
        const float* e1 = embeds + (size_t)p1.x * DFEAT;
        float v0 = __int_as_float(p0.y);
        float v1 = __int_as_float(p1.y);
        float x0 = e0[lane], y0 = e0[lane + 32], z0 = e0[lane + 64];
        float x1 = e1[lane], y1 = e1[lane + 32], z1 = e1[lane + 64];
        a0 += v0 * x0; a1 += v0 * y0; a2 += v0 * z0;
        a0 += v1 * x1; a1 += v1 * y1; a2 += v1 * z1;
    }
    if (i < end) {
        int2 p = pairs[i];
        const float* e = embeds + (size_t)p.x * DFEAT;
        float v = __int_as_float(p.y);
        a0 += v * e[lane]; a1 += v * e[lane + 32]; a2 += v * e[lane + 64];
    }
    float* o = out + (size_t)node * DFEAT;
    o[lane]      = a0;
    o[lane + 32] = a1;
    o[lane + 64] = a2;
}

// Last-resort fallback (R1 baseline).
__global__ void gcn_scatter_atomic_kernel(const int* __restrict__ rows, const int* __restrict__ cols,
                                          const float* __restrict__ vals, const float* __restrict__ embeds,
                                          float* __restrict__ out, int n_edges) {
    long long i = (long long)blockIdx.x * blockDim.x + threadIdx.x;
    long long total = (long long)n_edges * (DFEAT / 4);
    if (i >= total) return;
    int e = (int)(i / (DFEAT / 4));
    int q = (int)(i - (long long)e * (DFEAT / 4));
    int r = rows[e], c = cols[e];
    float v = vals[e];
    const float4* emb4 = reinterpret_cast<const float4*>(embeds + (long long)c * DFEAT);
    float4 x = emb4[q];
    float* o = out + (long long)r * DFEAT + q * 4;
    atomicAdd(o + 0, v * x.x);
    atomicAdd(o + 1, v * x.y);
    atomicAdd(o + 2, v * x.z);
    atomicAdd(o + 3, v * x.w);
}

extern "C" void kernel_launch(void* const* d_in, const int* in_sizes, int n_in,
                              void* d_out, int out_size, void* d_ws, size_t ws_size,
                              hipStream_t stream) {
    const int*   rows   = (const int*)d_in[0];
    const int*   cols   = (const int*)d_in[1];
    const float* vals   = (const float*)d_in[2];
    const float* embeds = (const float*)d_in[3];
    float*       out    = (float*)d_out;

    int E = in_sizes[0];
    int N = in_sizes[3] / DFEAT;
    int nb = (N + SCAN_BS - 1) / SCAN_BS;  // scan blocks

    // Workspace layout (ints unless noted):
    //   counts[N] | cursor[N] | offsets[N+1] | blockSums[nb] | blockOffs[nb]
    //   | rank[E] | pad | pairs[E] (int2)
    size_t head_ints_base = (size_t)(2 * N + (N + 1) + 2 * nb);
    size_t need_cursor = head_ints_base * sizeof(int) + 8 + (size_t)E * sizeof(int2);
    size_t need_rank   = (head_ints_base + (size_t)E) * sizeof(int) + 8 + (size_t)E * sizeof(int2);

    int eb = (E + 255) / 256;

    if (nb <= SCAN_BS && ws_size >= need_cursor) {
        bool use_rank = (ws_size >= need_rank);

        int* counts    = (int*)d_ws;
        int* cursor    = counts + N;
        int* offsets   = cursor + N;
        int* blockSums = offsets + (N + 1);
        int* blockOffs = blockSums + nb;
        int* rank      = blockOffs + nb;           // only valid if use_rank
        size_t head_bytes = (head_ints_base + (use_rank ? (size_t)E : 0)) * sizeof(int);
        head_bytes = (head_bytes + 7) & ~(size_t)7;  // align pairs to 8B
        int2* pairs = (int2*)((char*)d_ws + head_bytes);

        // Zero counts (+cursor if needed; adjacent).
        hipMemsetAsync(d_ws, 0, (size_t)(use_rank ? N : 2 * N) * sizeof(int), stream);

        hist_rank_kernel<<<eb, 256, 0, stream>>>(rows, counts, use_rank ? rank : cursor, E);
        if (!use_rank) {
            // cursor got clobbered by ranks; re-zero it (counts stays).
            hipMemsetAsync(cursor, 0, (size_t)N * sizeof(int), stream);
        }
        scan_blocks_kernel<<<nb, SCAN_BS, 0, stream>>>(counts, offsets, blockSums, N);
        scan_sums_kernel<<<1, SCAN_BS, 0, stream>>>(blockSums, blockOffs, nb);
        add_offsets_kernel<<<(N + 255) / 256, 256, 0, stream>>>(offsets, blockOffs, N, E);

        if (use_rank) {
            scatter_norank_kernel<<<eb, 256, 0, stream>>>(rows, cols, vals, offsets, rank, pairs, E);
        } else {
            scatter_cursor_kernel<<<eb, 256, 0, stream>>>(rows, cols, vals, offsets, cursor, pairs, E);
        }

        int nodes_per_block = 256 / 32;  // 8
        int gb = (N + nodes_per_block - 1) / nodes_per_block;
        accumulate_kernel<<<gb, 256, 0, stream>>>(pairs, offsets, embeds, out, N);
    } else {
        hipMemsetAsync(d_out, 0, (size_t)out_size * sizeof(float), stream);
        long long total = (long long)E * (DFEAT / 4);
        int block = 256;
        long long grid = (total + block - 1) / block;
        gcn_scatter_atomic_kernel<<<(int)grid, block, 0, stream>>>(rows, cols, vals, embeds, out, E);
    }
}